// Round 11
// baseline (2021.280 us; speedup 1.0000x reference)
//
#include <hip/hip_runtime.h>

#define T_STEPS 8

// ---- sizes (floats) ----
#define N_L1 (32*64*32*32)        // 2,097,152
#define N_S1P (32*64*34*34)       // 2,367,488  (padded spikes for conv2)
#define N_M2 (32*128*32*32)       // 4,194,304
#define N_P2P (32*128*18*20)      // 1,474,560  (padded pooled for conv3)
#define N_M3 (32*128*16*16)       // 1,048,576
#define N_P3 (32*8192)            // 262,144
#define N_C1 (32*1024)
#define N_C2 (32*10)

// ---- workspace offsets (floats) ----
#define OFF_A1  0
#define OFF_M1  (OFF_A1 + N_L1)
#define OFF_S1P (OFF_M1 + N_L1)
#define OFF_M2  (OFF_S1P + N_S1P)
#define OFF_P2P (OFF_M2 + N_M2)
#define OFF_M3  (OFF_P2P + N_P2P)
#define OFF_P3  (OFF_M3 + N_M3)
#define OFF_C1  (OFF_P3 + N_P3)
#define OFF_SF1 (OFF_C1 + N_C1)
#define OFF_C2  (OFF_SF1 + N_C1)
#define N_STATE (N_L1 + N_S1P + N_M2 + N_P2P + N_M3 + N_P3 + 2*N_C1 + N_C2)

// ---------------- conv1 (runs once; X constant across timesteps) ----------------
__global__ __launch_bounds__(256) void k_conv1(const float* __restrict__ X,
    const float* __restrict__ w, const float* __restrict__ bias,
    float* __restrict__ A1) {
  int idx = blockIdx.x * 256 + threadIdx.x;          // (b,oc,y,x)
  int x = idx & 31, y = (idx >> 5) & 31, oc = (idx >> 10) & 63, b = idx >> 16;
  float acc = bias[oc];
  for (int ic = 0; ic < 3; ++ic) {
    const float* xp = X + (b*3 + ic)*1024;
    const float* wp = w + (oc*3 + ic)*9;
    #pragma unroll
    for (int dy = 0; dy < 3; ++dy) {
      int iy = y + dy - 1;
      if (iy < 0 || iy > 31) continue;
      #pragma unroll
      for (int dx = 0; dx < 3; ++dx) {
        int ix = x + dx - 1;
        if (ix < 0 || ix > 31) continue;
        acc = fmaf(xp[iy*32 + ix], wp[dy*3 + dx], acc);
      }
    }
  }
  A1[idx] = acc;
}

// ---------------- layer-1 LIF + mask, writing PADDED spikes ----------------
// s1pad[b*64][34][34], interior (y+1, x+1); borders stay 0 (memset once per call).
__global__ __launch_bounds__(256) void k_lif1(const float4* __restrict__ A1,
    const float4* __restrict__ mask, float4* __restrict__ m1,
    float* __restrict__ s1pad) {
  int i = blockIdx.x * 256 + threadIdx.x;            // float4 index (N_L1/4)
  float4 m = m1[i], a = A1[i], k = mask[i];
  int x4 = (i & 7) * 4;
  int y  = (i >> 3) & 31;
  int plane = i >> 8;
  float* dst = s1pad + (size_t)plane*1156 + (y + 1)*34 + (x4 + 1);
  float p;
  m.x += a.x; p = (m.x >= 1.0f) ? 1.0f : 0.0f; m.x -= p; dst[0] = p * k.x;
  m.y += a.y; p = (m.y >= 1.0f) ? 1.0f : 0.0f; m.y -= p; dst[1] = p * k.y;
  m.z += a.z; p = (m.z >= 1.0f) ? 1.0f : 0.0f; m.z -= p; dst[2] = p * k.z;
  m.w += a.w; p = (m.w >= 1.0f) ? 1.0f : 0.0f; m.w -= p; dst[3] = p * k.w;
  m1[i] = m;
}

// ---------------- conv2 + LIF(m2) + 2x2 mean-pool (v4: linear staging) ----------------
// grid 1024: b(32) x yt(2) x ocg(16: 8 oc); block 256 = 16 xpair x 16 y
__global__ __launch_bounds__(256, 4) void k_conv2(const float* __restrict__ s1pad,
    const float* __restrict__ w, const float* __restrict__ bias,
    float* __restrict__ m2, float* __restrict__ p2pad) {
  int bid = blockIdx.x;
  int ocg = bid & 15;
  int yt  = (bid >> 4) & 1;
  int b   = bid >> 5;
  int t = threadIdx.x;
  int xp = t & 15, ty = t >> 4;           // x = {2xp, 2xp+1}, row = ty (0..15)

  __shared__ float lds[8 * 612];          // 8 ic x 18 rows x 34 cols = 19.6 KB
  float acc[2][8];
  #pragma unroll
  for (int o = 0; o < 8; ++o) { acc[0][o] = 0.f; acc[1][o] = 0.f; }

  for (int chunk = 0; chunk < 8; ++chunk) {
    const float* srcp = s1pad + (size_t)(b*64 + chunk*8)*1156 + yt*544; // 16*34
    __syncthreads();
    #pragma unroll
    for (int ic = 0; ic < 8; ++ic) {
      const float4* s4 = (const float4*)(srcp + ic*1156);
      float4* d4 = (float4*)(lds + ic*612);
      for (int j4 = t; j4 < 153; j4 += 256)
        d4[j4] = s4[j4];
    }
    __syncthreads();
    const float* wc = w + ((size_t)(ocg*8)*64 + chunk*8)*9;
    for (int ic = 0; ic < 8; ++ic) {
      float in12[12];
      const float* lp = &lds[ic*612 + ty*34 + 2*xp];
      #pragma unroll
      for (int dy = 0; dy < 3; ++dy)
        #pragma unroll
        for (int dx = 0; dx < 4; ++dx)
          in12[dy*4+dx] = lp[dy*34 + dx];
      #pragma unroll
      for (int o = 0; o < 8; ++o) {
        const float* wp = wc + (o*64 + ic)*9;   // block-uniform -> s_load
        #pragma unroll
        for (int k = 0; k < 9; ++k) {
          const int dy = k/3, dx = k - 3*(k/3);  // compile-time
          acc[0][o] = fmaf(in12[dy*4+dx],   wp[k], acc[0][o]);
          acc[1][o] = fmaf(in12[dy*4+dx+1], wp[k], acc[1][o]);
        }
      }
    }
  }

  int y = yt*16 + ty;
  int x0 = 2*xp;
  bool ywriter = ((ty & 1) == 0);
  #pragma unroll
  for (int o = 0; o < 8; ++o) {
    int oc = ocg*8 + o;
    size_t mi = (size_t)(b*128 + oc)*1024 + y*32 + x0;
    float2 mv = *(const float2*)&m2[mi];
    float ma = mv.x + acc[0][o] + bias[oc];
    float mb = mv.y + acc[1][o] + bias[oc];
    float sa = (ma >= 1.0f) ? 1.0f : 0.0f;
    float sb = (mb >= 1.0f) ? 1.0f : 0.0f;
    float2 mo; mo.x = ma - sa; mo.y = mb - sb;
    *(float2*)&m2[mi] = mo;
    float s = sa + sb;
    s += __shfl_xor(s, 16);
    if (ywriter)   // write pooled spike into padded conv3 input (interior +1,+1)
      p2pad[(size_t)(b*128 + oc)*360 + ((y>>1) + 1)*20 + (xp + 1)] = s * 0.25f;
  }
}

// ---------------- conv3 v6 + LIF(m3) + mask_f2 + 2x2 mean-pool ----------------
// grid 512 = b(32) x ocq(16: 8 oc); block 512 = oh(2: 4-oc half, t>>8) x y(16) x xp(8)
// per thread: 2 x-outputs x 4 oc; staging = 720 linear float4 copies (1.4/thread);
// 2 blocks/CU x 8 waves = 16 waves/CU (4/SIMD) -- double v5's occupancy.
__global__ __launch_bounds__(512, 4) void k_conv3(const float* __restrict__ p2pad,
    const float* __restrict__ w, const float* __restrict__ bias,
    const float* __restrict__ mf2, float* __restrict__ m3, float* __restrict__ p3) {
  int ocq = blockIdx.x & 15;
  int b   = blockIdx.x >> 4;
  int t = threadIdx.x;
  int xp = t & 7, y = (t >> 3) & 15, oh = t >> 8;
  // wave-uniform (t>>8 constant per 64-lane wave) -> weight reads stay s_loads
  int ocb = __builtin_amdgcn_readfirstlane(ocq*8 + oh*4);

  __shared__ float lds[8 * 360];          // 8 ic x 18 x 20 = 11.5 KB
  float acc[2][4];
  #pragma unroll
  for (int o = 0; o < 4; ++o) { acc[0][o] = 0.f; acc[1][o] = 0.f; }

  for (int chunk = 0; chunk < 16; ++chunk) {
    const float4* srcp4 = (const float4*)(p2pad + (size_t)(b*128 + chunk*8)*360);
    __syncthreads();
    for (int j4 = t; j4 < 720; j4 += 512)
      ((float4*)lds)[j4] = srcp4[j4];
    __syncthreads();
    const float* wc = w + ((size_t)ocb*128 + chunk*8)*9;
    for (int ic = 0; ic < 8; ++ic) {
      float in12[12];
      const float* lp = &lds[ic*360 + y*20 + 2*xp];
      #pragma unroll
      for (int dy = 0; dy < 3; ++dy)
        #pragma unroll
        for (int dx = 0; dx < 4; ++dx)
          in12[dy*4+dx] = lp[dy*20 + dx];
      #pragma unroll
      for (int o = 0; o < 4; ++o) {
        const float* wp = wc + (o*128 + ic)*9;  // SGPR-uniform -> s_load
        #pragma unroll
        for (int k = 0; k < 9; ++k) {
          const int dy = k/3, dx = k - 3*(k/3);  // compile-time
          acc[0][o] = fmaf(in12[dy*4+dx],   wp[k], acc[0][o]);
          acc[1][o] = fmaf(in12[dy*4+dx+1], wp[k], acc[1][o]);
        }
      }
    }
  }

  // epilogue: bias + LIF + mask-before-pool; x-pair in-thread (exact products,
  // same combine order as before), y-pair via shfl_xor(8) (y bit0 = lane bit3)
  int x0 = 2*xp;
  bool ywriter = ((y & 1) == 0);
  #pragma unroll
  for (int o = 0; o < 4; ++o) {
    int oc = ocb + o;
    size_t base = (size_t)(b*128 + oc)*256 + y*16 + x0;
    float2 mv = *(const float2*)&m3[base];
    float2 fv = *(const float2*)&mf2[base];
    float ma = mv.x + acc[0][o] + bias[oc];
    float mb = mv.y + acc[1][o] + bias[oc];
    float sa = (ma >= 1.0f) ? 1.0f : 0.0f;
    float sb = (mb >= 1.0f) ? 1.0f : 0.0f;
    float2 mo; mo.x = ma - sa; mo.y = mb - sb;
    *(float2*)&m3[base] = mo;
    float s = sa * fv.x + sb * fv.y;
    s += __shfl_xor(s, 8);
    if (ywriter)
      p3[(size_t)b*8192 + oc*64 + (y>>1)*8 + xp] = s * 0.25f;
  }
}

// ---------------- fc1 v4: LDS-staged, order-preserving serial chain ----------------
// grid 256 = ug(128: 8 u) x bg(2: 16 b); block 128 = 8 u-lanes x 16 b
__global__ __launch_bounds__(128) void k_fc1v4(const float* __restrict__ p3,
    const float* __restrict__ w, const float* __restrict__ bias,
    const float* __restrict__ mask, float* __restrict__ c1, float* __restrict__ sf1) {
  const float4* w4  = (const float4*)w;
  const float4* p34 = (const float4*)p3;
  int ug = blockIdx.x >> 1;
  int bg = blockIdx.x & 1;
  int u0 = ug * 8, b0 = bg * 16;
  int t = threadIdx.x;
  int u_l = t & 7, b_sub = t >> 3;       // u fastest -> coalesced c1/sf1 epilogue

  __shared__ float4 lds4[8*130 + 16*129];  // w | s = 49.7 KB
  float4* wl = lds4;
  float4* sl = lds4 + 8*130;

  float acc = 0.f;
  for (int kc = 0; kc < 16; ++kc) {
    __syncthreads();
    #pragma unroll
    for (int j0 = 0; j0 < 1024; j0 += 128) {
      int j = j0 + t;
      int u_i = j >> 7, k4 = j & 127;
      wl[u_i*130 + k4] = w4[(size_t)(u0 + u_i)*2048 + kc*128 + k4];
    }
    #pragma unroll
    for (int j0 = 0; j0 < 2048; j0 += 128) {
      int j = j0 + t;
      int b_i = j >> 7, k4 = j & 127;
      sl[b_i*129 + k4] = p34[(size_t)(b0 + b_i)*2048 + kc*128 + k4];
    }
    __syncthreads();
    const float4* wp = wl + u_l*130;
    const float4* sp = sl + b_sub*129;
    #pragma unroll 8
    for (int k4 = 0; k4 < 128; ++k4) {
      float4 wv = wp[k4];
      float4 sv = sp[k4];
      acc = fmaf(wv.x, sv.x, acc);
      acc = fmaf(wv.y, sv.y, acc);
      acc = fmaf(wv.z, sv.z, acc);
      acc = fmaf(wv.w, sv.w, acc);
    }
  }

  int u = u0 + u_l, b = b0 + b_sub;
  int mi = b * 1024 + u;
  float m = c1[mi] + acc + bias[u];
  float spk = (m >= 1.0f) ? 1.0f : 0.0f;
  c1[mi] = m - spk;
  sf1[mi] = spk * mask[mi];
}

// ---------------- fc2 (32x1024 @ 1024x10^T) + LIF(c2) -> out ----------------
__global__ __launch_bounds__(256) void k_fc2(const float* __restrict__ sf1,
    const float* __restrict__ w, const float* __restrict__ bias,
    float* __restrict__ c2, float* __restrict__ out) {
  int idx = blockIdx.x * 256 + threadIdx.x;
  if (idx >= 320) return;
  int u = idx >> 5;      // 0..9
  int b = idx & 31;
  const float4* wp = (const float4*)(w + u * 1024);
  const float4* sp = (const float4*)(sf1 + b * 1024);
  float acc = 0.f;
  #pragma unroll 4
  for (int i = 0; i < 256; ++i) {
    float4 a = wp[i];
    float4 s = sp[i];
    acc = fmaf(a.x, s.x, acc);
    acc = fmaf(a.y, s.y, acc);
    acc = fmaf(a.z, s.z, acc);
    acc = fmaf(a.w, s.w, acc);
  }
  int mi = b * 10 + u;
  float m = c2[mi] + acc + bias[u];
  float spk = (m >= 1.0f) ? 1.0f : 0.0f;
  m -= spk;
  c2[mi] = m;
  out[mi] = m;   // final timestep's write is the answer
}

extern "C" void kernel_launch(void* const* d_in, const int* in_sizes, int n_in,
                              void* d_out, int out_size, void* d_ws, size_t ws_size,
                              hipStream_t stream) {
  const float* X   = (const float*)d_in[0];
  const float* w1  = (const float*)d_in[1];
  const float* b1  = (const float*)d_in[2];
  const float* w2  = (const float*)d_in[3];
  const float* b2  = (const float*)d_in[4];
  const float* w3  = (const float*)d_in[5];
  const float* b3  = (const float*)d_in[6];
  const float* fw1 = (const float*)d_in[7];
  const float* fb1 = (const float*)d_in[8];
  const float* fw2 = (const float*)d_in[9];
  const float* fb2 = (const float*)d_in[10];
  const float* mf1 = (const float*)d_in[11];
  const float* mf2 = (const float*)d_in[12];
  const float* mc1 = (const float*)d_in[13];
  float* out = (float*)d_out;

  float* ws    = (float*)d_ws;
  float* A1    = ws + OFF_A1;
  float* m1    = ws + OFF_M1;
  float* s1pad = ws + OFF_S1P;
  float* m2    = ws + OFF_M2;
  float* p2pad = ws + OFF_P2P;
  float* m3    = ws + OFF_M3;
  float* p3    = ws + OFF_P3;
  float* c1    = ws + OFF_C1;
  float* sf1   = ws + OFF_SF1;
  float* c2    = ws + OFF_C2;

  // ws is poisoned 0xAA before every timed call: zero LIF state AND padded
  // buffers (borders must be 0). m1..c2 are contiguous -> single memset.
  hipMemsetAsync(m1, 0, (size_t)(N_STATE - N_L1) * 4, stream);

  // conv1 output is timestep-invariant: compute once.
  k_conv1<<<N_L1/256, 256, 0, stream>>>(X, w1, b1, A1);

  for (int t = 0; t < T_STEPS; ++t) {
    k_lif1<<<N_L1/4/256, 256, 0, stream>>>((const float4*)A1, (const float4*)mf1,
                                           (float4*)m1, s1pad);
    k_conv2<<<1024, 256, 0, stream>>>(s1pad, w2, b2, m2, p2pad);
    k_conv3<<<512, 512, 0, stream>>>(p2pad, w3, b3, mf2, m3, p3);
    k_fc1v4<<<256, 128, 0, stream>>>(p3, fw1, fb1, mc1, c1, sf1);
    k_fc2<<<2, 256, 0, stream>>>(sf1, fw2, fb2, c2, out);
  }
}

// Round 12
// 1953.251 us; speedup vs baseline: 1.0348x; 1.0348x over previous
//
#include <hip/hip_runtime.h>

#define T_STEPS 8

// ---- sizes (floats) ----
#define N_L1 (32*64*32*32)        // 2,097,152
#define N_S1P (32*64*34*34)       // 2,367,488  (padded spikes for conv2)
#define N_M2 (32*128*32*32)       // 4,194,304
#define N_P2P (32*128*18*20)      // 1,474,560  (padded pooled for conv3)
#define N_M3 (32*128*16*16)       // 1,048,576
#define N_P3 (32*8192)            // 262,144
#define N_C1 (32*1024)
#define N_C2 (32*10)

// ---- workspace offsets (floats) ----
#define OFF_A1  0
#define OFF_M1  (OFF_A1 + N_L1)
#define OFF_S1P (OFF_M1 + N_L1)
#define OFF_M2  (OFF_S1P + N_S1P)
#define OFF_P2P (OFF_M2 + N_M2)
#define OFF_M3  (OFF_P2P + N_P2P)
#define OFF_P3  (OFF_M3 + N_M3)
#define OFF_C1  (OFF_P3 + N_P3)
#define OFF_SF1 (OFF_C1 + N_C1)
#define OFF_C2  (OFF_SF1 + N_C1)
#define N_STATE (N_L1 + N_S1P + N_M2 + N_P2P + N_M3 + N_P3 + 2*N_C1 + N_C2)

// ---------------- conv1 (runs once; X constant across timesteps) ----------------
__global__ __launch_bounds__(256) void k_conv1(const float* __restrict__ X,
    const float* __restrict__ w, const float* __restrict__ bias,
    float* __restrict__ A1) {
  int idx = blockIdx.x * 256 + threadIdx.x;          // (b,oc,y,x)
  int x = idx & 31, y = (idx >> 5) & 31, oc = (idx >> 10) & 63, b = idx >> 16;
  float acc = bias[oc];
  for (int ic = 0; ic < 3; ++ic) {
    const float* xp = X + (b*3 + ic)*1024;
    const float* wp = w + (oc*3 + ic)*9;
    #pragma unroll
    for (int dy = 0; dy < 3; ++dy) {
      int iy = y + dy - 1;
      if (iy < 0 || iy > 31) continue;
      #pragma unroll
      for (int dx = 0; dx < 3; ++dx) {
        int ix = x + dx - 1;
        if (ix < 0 || ix > 31) continue;
        acc = fmaf(xp[iy*32 + ix], wp[dy*3 + dx], acc);
      }
    }
  }
  A1[idx] = acc;
}

// ---------------- layer-1 LIF + mask, writing PADDED spikes ----------------
// s1pad[b*64][34][34], interior (y+1, x+1); borders stay 0 (memset once per call).
__global__ __launch_bounds__(256) void k_lif1(const float4* __restrict__ A1,
    const float4* __restrict__ mask, float4* __restrict__ m1,
    float* __restrict__ s1pad) {
  int i = blockIdx.x * 256 + threadIdx.x;            // float4 index (N_L1/4)
  float4 m = m1[i], a = A1[i], k = mask[i];
  int x4 = (i & 7) * 4;
  int y  = (i >> 3) & 31;
  int plane = i >> 8;
  float* dst = s1pad + (size_t)plane*1156 + (y + 1)*34 + (x4 + 1);
  float p;
  m.x += a.x; p = (m.x >= 1.0f) ? 1.0f : 0.0f; m.x -= p; dst[0] = p * k.x;
  m.y += a.y; p = (m.y >= 1.0f) ? 1.0f : 0.0f; m.y -= p; dst[1] = p * k.y;
  m.z += a.z; p = (m.z >= 1.0f) ? 1.0f : 0.0f; m.z -= p; dst[2] = p * k.z;
  m.w += a.w; p = (m.w >= 1.0f) ? 1.0f : 0.0f; m.w -= p; dst[3] = p * k.w;
  m1[i] = m;
}

// ---------------- conv2 + LIF(m2) + 2x2 mean-pool (v4: linear staging) ----------------
// grid 1024: b(32) x yt(2) x ocg(16: 8 oc); block 256 = 16 xpair x 16 y
__global__ __launch_bounds__(256, 4) void k_conv2(const float* __restrict__ s1pad,
    const float* __restrict__ w, const float* __restrict__ bias,
    float* __restrict__ m2, float* __restrict__ p2pad) {
  int bid = blockIdx.x;
  int ocg = bid & 15;
  int yt  = (bid >> 4) & 1;
  int b   = bid >> 5;
  int t = threadIdx.x;
  int xp = t & 15, ty = t >> 4;           // x = {2xp, 2xp+1}, row = ty (0..15)

  __shared__ float lds[8 * 612];          // 8 ic x 18 rows x 34 cols = 19.6 KB
  float acc[2][8];
  #pragma unroll
  for (int o = 0; o < 8; ++o) { acc[0][o] = 0.f; acc[1][o] = 0.f; }

  for (int chunk = 0; chunk < 8; ++chunk) {
    const float* srcp = s1pad + (size_t)(b*64 + chunk*8)*1156 + yt*544; // 16*34
    __syncthreads();
    #pragma unroll
    for (int ic = 0; ic < 8; ++ic) {
      const float4* s4 = (const float4*)(srcp + ic*1156);
      float4* d4 = (float4*)(lds + ic*612);
      for (int j4 = t; j4 < 153; j4 += 256)
        d4[j4] = s4[j4];
    }
    __syncthreads();
    const float* wc = w + ((size_t)(ocg*8)*64 + chunk*8)*9;
    for (int ic = 0; ic < 8; ++ic) {
      float in12[12];
      const float* lp = &lds[ic*612 + ty*34 + 2*xp];
      #pragma unroll
      for (int dy = 0; dy < 3; ++dy)
        #pragma unroll
        for (int dx = 0; dx < 4; ++dx)
          in12[dy*4+dx] = lp[dy*34 + dx];
      #pragma unroll
      for (int o = 0; o < 8; ++o) {
        const float* wp = wc + (o*64 + ic)*9;   // block-uniform -> s_load
        #pragma unroll
        for (int k = 0; k < 9; ++k) {
          const int dy = k/3, dx = k - 3*(k/3);  // compile-time
          acc[0][o] = fmaf(in12[dy*4+dx],   wp[k], acc[0][o]);
          acc[1][o] = fmaf(in12[dy*4+dx+1], wp[k], acc[1][o]);
        }
      }
    }
  }

  int y = yt*16 + ty;
  int x0 = 2*xp;
  bool ywriter = ((ty & 1) == 0);
  #pragma unroll
  for (int o = 0; o < 8; ++o) {
    int oc = ocg*8 + o;
    size_t mi = (size_t)(b*128 + oc)*1024 + y*32 + x0;
    float2 mv = *(const float2*)&m2[mi];
    float ma = mv.x + acc[0][o] + bias[oc];
    float mb = mv.y + acc[1][o] + bias[oc];
    float sa = (ma >= 1.0f) ? 1.0f : 0.0f;
    float sb = (mb >= 1.0f) ? 1.0f : 0.0f;
    float2 mo; mo.x = ma - sa; mo.y = mb - sb;
    *(float2*)&m2[mi] = mo;
    float s = sa + sb;
    s += __shfl_xor(s, 16);
    if (ywriter)   // write pooled spike into padded conv3 input (interior +1,+1)
      p2pad[(size_t)(b*128 + oc)*360 + ((y>>1) + 1)*20 + (xp + 1)] = s * 0.25f;
  }
}

// ---------------- conv3 v7 + LIF(m3) + mask_f2 + 2x2 mean-pool ----------------
// grid 1024 = b(32) x ocg(16: 8 oc) x yt(2: 8-row bands)
// block 256 = og2(2: 4 oc, t>>7) x y(8, (t>>4)&7) x x(16, t&15)  -- all bits used
// per thread: 1 x-output x 4 oc; LDS chunk 8 ic x 10 rows x 20 = 6.4 KB,
// staged as static linear float4 copies (ic = t>>5, r = t&31; no div, coalesced).
// 4 blocks/CU -> 16 waves/CU; independent blocks overlap each other's stage stalls.
__global__ __launch_bounds__(256, 4) void k_conv3(const float* __restrict__ p2pad,
    const float* __restrict__ w, const float* __restrict__ bias,
    const float* __restrict__ mf2, float* __restrict__ m3, float* __restrict__ p3) {
  int bid = blockIdx.x;
  int yt  = bid & 1;
  int ocg = (bid >> 1) & 15;
  int b   = bid >> 5;
  int t = threadIdx.x;
  int x = t & 15, y = (t >> 4) & 7, og2 = t >> 7;
  // wave-uniform (t>>7 constant per 64-lane wave) -> weight reads stay s_loads
  int ocb = __builtin_amdgcn_readfirstlane(ocg*8 + og2*4);

  __shared__ float lds[8 * 200];          // 8 ic x 10 rows x 20 cols = 6.4 KB
  float acc[4];
  #pragma unroll
  for (int o = 0; o < 4; ++o) acc[o] = 0.f;

  int ic_s = t >> 5, r0 = t & 31;         // static staging decode: 32 thr per ic
  for (int chunk = 0; chunk < 16; ++chunk) {
    const float4* src4 = (const float4*)(p2pad
        + (size_t)(b*128 + chunk*8 + ic_s)*360 + yt*160);   // rows yt*8..yt*8+9
    float4* dst4 = (float4*)(lds + ic_s*200);
    __syncthreads();
    dst4[r0] = src4[r0];                  // 50 f4 per ic: 32 + 18
    if (r0 < 18) dst4[32 + r0] = src4[32 + r0];
    __syncthreads();
    const float* wc = w + ((size_t)ocb*128 + chunk*8)*9;
    for (int ic = 0; ic < 8; ++ic) {
      float in9[9];
      const float* lp = &lds[ic*200 + y*20 + x];
      #pragma unroll
      for (int dy = 0; dy < 3; ++dy)
        #pragma unroll
        for (int dx = 0; dx < 3; ++dx)
          in9[dy*3+dx] = lp[dy*20 + dx];
      #pragma unroll
      for (int o = 0; o < 4; ++o) {
        const float* wp = wc + (o*128 + ic)*9;  // SGPR-uniform -> s_load
        #pragma unroll
        for (int k = 0; k < 9; ++k)
          acc[o] = fmaf(in9[k], wp[k], acc[o]);
      }
    }
  }

  // epilogue identical order to v1 (verified bit-exact): mask before pool,
  // x-pair via shfl_xor(1) (x bit0 = lane bit0), y-pair via shfl_xor(16) (y bit0 = lane bit4)
  int y_out = yt*8 + y;
  bool writer = ((x & 1) == 0) && ((y & 1) == 0);
  #pragma unroll
  for (int o = 0; o < 4; ++o) {
    int oc = ocb + o;
    size_t base = (size_t)(b*128 + oc)*256 + y_out*16 + x;
    float m = m3[base] + acc[o] + bias[oc];
    float spk = (m >= 1.0f) ? 1.0f : 0.0f;
    m3[base] = m - spk;
    float s = spk * mf2[base];
    s += __shfl_xor(s, 1);
    s += __shfl_xor(s, 16);
    if (writer)
      p3[(size_t)b*8192 + oc*64 + (y_out>>1)*8 + (x>>1)] = s * 0.25f;
  }
}

// ---------------- fc1 v4: LDS-staged, order-preserving serial chain ----------------
// grid 256 = ug(128: 8 u) x bg(2: 16 b); block 128 = 8 u-lanes x 16 b
__global__ __launch_bounds__(128) void k_fc1v4(const float* __restrict__ p3,
    const float* __restrict__ w, const float* __restrict__ bias,
    const float* __restrict__ mask, float* __restrict__ c1, float* __restrict__ sf1) {
  const float4* w4  = (const float4*)w;
  const float4* p34 = (const float4*)p3;
  int ug = blockIdx.x >> 1;
  int bg = blockIdx.x & 1;
  int u0 = ug * 8, b0 = bg * 16;
  int t = threadIdx.x;
  int u_l = t & 7, b_sub = t >> 3;       // u fastest -> coalesced c1/sf1 epilogue

  __shared__ float4 lds4[8*130 + 16*129];  // w | s = 49.7 KB
  float4* wl = lds4;
  float4* sl = lds4 + 8*130;

  float acc = 0.f;
  for (int kc = 0; kc < 16; ++kc) {
    __syncthreads();
    #pragma unroll
    for (int j0 = 0; j0 < 1024; j0 += 128) {
      int j = j0 + t;
      int u_i = j >> 7, k4 = j & 127;
      wl[u_i*130 + k4] = w4[(size_t)(u0 + u_i)*2048 + kc*128 + k4];
    }
    #pragma unroll
    for (int j0 = 0; j0 < 2048; j0 += 128) {
      int j = j0 + t;
      int b_i = j >> 7, k4 = j & 127;
      sl[b_i*129 + k4] = p34[(size_t)(b0 + b_i)*2048 + kc*128 + k4];
    }
    __syncthreads();
    const float4* wp = wl + u_l*130;
    const float4* sp = sl + b_sub*129;
    #pragma unroll 8
    for (int k4 = 0; k4 < 128; ++k4) {
      float4 wv = wp[k4];
      float4 sv = sp[k4];
      acc = fmaf(wv.x, sv.x, acc);
      acc = fmaf(wv.y, sv.y, acc);
      acc = fmaf(wv.z, sv.z, acc);
      acc = fmaf(wv.w, sv.w, acc);
    }
  }

  int u = u0 + u_l, b = b0 + b_sub;
  int mi = b * 1024 + u;
  float m = c1[mi] + acc + bias[u];
  float spk = (m >= 1.0f) ? 1.0f : 0.0f;
  c1[mi] = m - spk;
  sf1[mi] = spk * mask[mi];
}

// ---------------- fc2 (32x1024 @ 1024x10^T) + LIF(c2) -> out ----------------
__global__ __launch_bounds__(256) void k_fc2(const float* __restrict__ sf1,
    const float* __restrict__ w, const float* __restrict__ bias,
    float* __restrict__ c2, float* __restrict__ out) {
  int idx = blockIdx.x * 256 + threadIdx.x;
  if (idx >= 320) return;
  int u = idx >> 5;      // 0..9
  int b = idx & 31;
  const float4* wp = (const float4*)(w + u * 1024);
  const float4* sp = (const float4*)(sf1 + b * 1024);
  float acc = 0.f;
  #pragma unroll 4
  for (int i = 0; i < 256; ++i) {
    float4 a = wp[i];
    float4 s = sp[i];
    acc = fmaf(a.x, s.x, acc);
    acc = fmaf(a.y, s.y, acc);
    acc = fmaf(a.z, s.z, acc);
    acc = fmaf(a.w, s.w, acc);
  }
  int mi = b * 10 + u;
  float m = c2[mi] + acc + bias[u];
  float spk = (m >= 1.0f) ? 1.0f : 0.0f;
  m -= spk;
  c2[mi] = m;
  out[mi] = m;   // final timestep's write is the answer
}

extern "C" void kernel_launch(void* const* d_in, const int* in_sizes, int n_in,
                              void* d_out, int out_size, void* d_ws, size_t ws_size,
                              hipStream_t stream) {
  const float* X   = (const float*)d_in[0];
  const float* w1  = (const float*)d_in[1];
  const float* b1  = (const float*)d_in[2];
  const float* w2  = (const float*)d_in[3];
  const float* b2  = (const float*)d_in[4];
  const float* w3  = (const float*)d_in[5];
  const float* b3  = (const float*)d_in[6];
  const float* fw1 = (const float*)d_in[7];
  const float* fb1 = (const float*)d_in[8];
  const float* fw2 = (const float*)d_in[9];
  const float* fb2 = (const float*)d_in[10];
  const float* mf1 = (const float*)d_in[11];
  const float* mf2 = (const float*)d_in[12];
  const float* mc1 = (const float*)d_in[13];
  float* out = (float*)d_out;

  float* ws    = (float*)d_ws;
  float* A1    = ws + OFF_A1;
  float* m1    = ws + OFF_M1;
  float* s1pad = ws + OFF_S1P;
  float* m2    = ws + OFF_M2;
  float* p2pad = ws + OFF_P2P;
  float* m3    = ws + OFF_M3;
  float* p3    = ws + OFF_P3;
  float* c1    = ws + OFF_C1;
  float* sf1   = ws + OFF_SF1;
  float* c2    = ws + OFF_C2;

  // ws is poisoned 0xAA before every timed call: zero LIF state AND padded
  // buffers (borders must be 0). m1..c2 are contiguous -> single memset.
  hipMemsetAsync(m1, 0, (size_t)(N_STATE - N_L1) * 4, stream);

  // conv1 output is timestep-invariant: compute once.
  k_conv1<<<N_L1/256, 256, 0, stream>>>(X, w1, b1, A1);

  for (int t = 0; t < T_STEPS; ++t) {
    k_lif1<<<N_L1/4/256, 256, 0, stream>>>((const float4*)A1, (const float4*)mf1,
                                           (float4*)m1, s1pad);
    k_conv2<<<1024, 256, 0, stream>>>(s1pad, w2, b2, m2, p2pad);
    k_conv3<<<1024, 256, 0, stream>>>(p2pad, w3, b3, mf2, m3, p3);
    k_fc1v4<<<256, 128, 0, stream>>>(p3, fw1, fb1, mc1, c1, sf1);
    k_fc2<<<2, 256, 0, stream>>>(sf1, fw2, fb2, c2, out);
  }
}

// Round 13
// 1918.023 us; speedup vs baseline: 1.0538x; 1.0184x over previous
//
#include <hip/hip_runtime.h>

#define T_STEPS 8

// ---- sizes (floats) ----
#define N_L1 (32*64*32*32)        // 2,097,152
#define N_S1P (32*64*34*34)       // 2,367,488  (padded spikes for conv2)
#define N_M2 (32*128*32*32)       // 4,194,304
#define N_P2P (32*128*18*20)      // 1,474,560  (padded pooled for conv3)
#define N_M3 (32*128*16*16)       // 1,048,576
#define N_P3 (32*8192)            // 262,144
#define N_C1 (32*1024)
#define N_C2 (32*10)

// ---- workspace offsets (floats) ----
#define OFF_A1  0
#define OFF_M1  (OFF_A1 + N_L1)
#define OFF_S1P (OFF_M1 + N_L1)
#define OFF_M2  (OFF_S1P + N_S1P)
#define OFF_P2P (OFF_M2 + N_M2)
#define OFF_M3  (OFF_P2P + N_P2P)
#define OFF_P3  (OFF_M3 + N_M3)
#define OFF_C1  (OFF_P3 + N_P3)
#define OFF_SF1 (OFF_C1 + N_C1)
#define OFF_C2  (OFF_SF1 + N_C1)
// everything after A1 must be zeroed (LIF state + padded-buffer borders)
#define N_ZERO  (OFF_C2 + N_C2 - OFF_M1)

// ---------------- conv1 (runs once; X constant across timesteps) ----------------
__global__ __launch_bounds__(256) void k_conv1(const float* __restrict__ X,
    const float* __restrict__ w, const float* __restrict__ bias,
    float* __restrict__ A1) {
  int idx = blockIdx.x * 256 + threadIdx.x;          // (b,oc,y,x)
  int x = idx & 31, y = (idx >> 5) & 31, oc = (idx >> 10) & 63, b = idx >> 16;
  float acc = bias[oc];
  for (int ic = 0; ic < 3; ++ic) {
    const float* xp = X + (b*3 + ic)*1024;
    const float* wp = w + (oc*3 + ic)*9;
    #pragma unroll
    for (int dy = 0; dy < 3; ++dy) {
      int iy = y + dy - 1;
      if (iy < 0 || iy > 31) continue;
      #pragma unroll
      for (int dx = 0; dx < 3; ++dx) {
        int ix = x + dx - 1;
        if (ix < 0 || ix > 31) continue;
        acc = fmaf(xp[iy*32 + ix], wp[dy*3 + dx], acc);
      }
    }
  }
  A1[idx] = acc;
}

// ---------------- layer-1 LIF + mask, writing PADDED spikes ----------------
// s1pad[b*64][34][34], interior (y+1, x+1); borders stay 0 (memset once per call).
__global__ __launch_bounds__(256) void k_lif1(const float4* __restrict__ A1,
    const float4* __restrict__ mask, float4* __restrict__ m1,
    float* __restrict__ s1pad) {
  int i = blockIdx.x * 256 + threadIdx.x;            // float4 index (N_L1/4)
  float4 m = m1[i], a = A1[i], k = mask[i];
  int x4 = (i & 7) * 4;
  int y  = (i >> 3) & 31;
  int plane = i >> 8;
  float* dst = s1pad + (size_t)plane*1156 + (y + 1)*34 + (x4 + 1);
  float p;
  m.x += a.x; p = (m.x >= 1.0f) ? 1.0f : 0.0f; m.x -= p; dst[0] = p * k.x;
  m.y += a.y; p = (m.y >= 1.0f) ? 1.0f : 0.0f; m.y -= p; dst[1] = p * k.y;
  m.z += a.z; p = (m.z >= 1.0f) ? 1.0f : 0.0f; m.z -= p; dst[2] = p * k.z;
  m.w += a.w; p = (m.w >= 1.0f) ? 1.0f : 0.0f; m.w -= p; dst[3] = p * k.w;
  m1[i] = m;
}

// ---------------- conv2 + LIF(m2) + 2x2 mean-pool (v4: linear staging) ----------------
// grid 1024: b(32) x yt(2) x ocg(16: 8 oc); block 256 = 16 xpair x 16 y
__global__ __launch_bounds__(256, 4) void k_conv2(const float* __restrict__ s1pad,
    const float* __restrict__ w, const float* __restrict__ bias,
    float* __restrict__ m2, float* __restrict__ p2pad) {
  int bid = blockIdx.x;
  int ocg = bid & 15;
  int yt  = (bid >> 4) & 1;
  int b   = bid >> 5;
  int t = threadIdx.x;
  int xp = t & 15, ty = t >> 4;           // x = {2xp, 2xp+1}, row = ty (0..15)

  __shared__ float lds[8 * 612];          // 8 ic x 18 rows x 34 cols = 19.6 KB
  float acc[2][8];
  #pragma unroll
  for (int o = 0; o < 8; ++o) { acc[0][o] = 0.f; acc[1][o] = 0.f; }

  for (int chunk = 0; chunk < 8; ++chunk) {
    const float* srcp = s1pad + (size_t)(b*64 + chunk*8)*1156 + yt*544; // 16*34
    __syncthreads();
    #pragma unroll
    for (int ic = 0; ic < 8; ++ic) {
      const float4* s4 = (const float4*)(srcp + ic*1156);
      float4* d4 = (float4*)(lds + ic*612);
      for (int j4 = t; j4 < 153; j4 += 256)
        d4[j4] = s4[j4];
    }
    __syncthreads();
    const float* wc = w + ((size_t)(ocg*8)*64 + chunk*8)*9;
    for (int ic = 0; ic < 8; ++ic) {
      float in12[12];
      const float* lp = &lds[ic*612 + ty*34 + 2*xp];
      #pragma unroll
      for (int dy = 0; dy < 3; ++dy)
        #pragma unroll
        for (int dx = 0; dx < 4; ++dx)
          in12[dy*4+dx] = lp[dy*34 + dx];
      #pragma unroll
      for (int o = 0; o < 8; ++o) {
        const float* wp = wc + (o*64 + ic)*9;   // block-uniform -> s_load
        #pragma unroll
        for (int k = 0; k < 9; ++k) {
          const int dy = k/3, dx = k - 3*(k/3);  // compile-time
          acc[0][o] = fmaf(in12[dy*4+dx],   wp[k], acc[0][o]);
          acc[1][o] = fmaf(in12[dy*4+dx+1], wp[k], acc[1][o]);
        }
      }
    }
  }

  int y = yt*16 + ty;
  int x0 = 2*xp;
  bool ywriter = ((ty & 1) == 0);
  #pragma unroll
  for (int o = 0; o < 8; ++o) {
    int oc = ocg*8 + o;
    size_t mi = (size_t)(b*128 + oc)*1024 + y*32 + x0;
    float2 mv = *(const float2*)&m2[mi];
    float ma = mv.x + acc[0][o] + bias[oc];
    float mb = mv.y + acc[1][o] + bias[oc];
    float sa = (ma >= 1.0f) ? 1.0f : 0.0f;
    float sb = (mb >= 1.0f) ? 1.0f : 0.0f;
    float2 mo; mo.x = ma - sa; mo.y = mb - sb;
    *(float2*)&m2[mi] = mo;
    float s = sa + sb;
    s += __shfl_xor(s, 16);
    if (ywriter)   // write pooled spike into padded conv3 input (interior +1,+1)
      p2pad[(size_t)(b*128 + oc)*360 + ((y>>1) + 1)*20 + (xp + 1)] = s * 0.25f;
  }
}

// ---------------- conv3 v8 + LIF(m3) + mask_f2 + 2x2 mean-pool ----------------
// grid 1024 = b(32) x ocg(16: 8 oc) x yt(2: 8-row bands)
// block 256 = og2(2: 4 oc, t>>7) x y(8, (t>>4)&7) x x(16, t&15)  -- all bits used
// 8 chunks of 16 ic (was 16 of 8): half the barrier/stall rounds, 576 FMA/round.
// LDS 16 ic x 10 rows x 20 = 12.8 KB; staging static linear f4 (ic = t>>4, r = t&15).
__global__ __launch_bounds__(256, 4) void k_conv3(const float* __restrict__ p2pad,
    const float* __restrict__ w, const float* __restrict__ bias,
    const float* __restrict__ mf2, float* __restrict__ m3, float* __restrict__ p3) {
  int bid = blockIdx.x;
  int yt  = bid & 1;
  int ocg = (bid >> 1) & 15;
  int b   = bid >> 5;
  int t = threadIdx.x;
  int x = t & 15, y = (t >> 4) & 7, og2 = t >> 7;
  // wave-uniform (t>>7 constant per 64-lane wave) -> weight reads stay s_loads
  int ocb = __builtin_amdgcn_readfirstlane(ocg*8 + og2*4);

  __shared__ float lds[16 * 200];         // 16 ic x 10 rows x 20 cols = 12.8 KB
  float acc[4];
  #pragma unroll
  for (int o = 0; o < 4; ++o) acc[o] = 0.f;

  int ic_s = t >> 4, r0 = t & 15;         // static staging decode: 16 thr per ic
  for (int chunk = 0; chunk < 8; ++chunk) {
    const float4* src4 = (const float4*)(p2pad
        + (size_t)(b*128 + chunk*16 + ic_s)*360 + yt*160);  // rows yt*8..yt*8+9
    float4* dst4 = (float4*)(lds + ic_s*200);
    __syncthreads();
    dst4[r0]      = src4[r0];             // 50 f4 per ic: 16+16+16+2
    dst4[16 + r0] = src4[16 + r0];
    dst4[32 + r0] = src4[32 + r0];
    if (r0 < 2) dst4[48 + r0] = src4[48 + r0];
    __syncthreads();
    const float* wc = w + ((size_t)ocb*128 + chunk*16)*9;
    for (int ic = 0; ic < 16; ++ic) {
      float in9[9];
      const float* lp = &lds[ic*200 + y*20 + x];
      #pragma unroll
      for (int dy = 0; dy < 3; ++dy)
        #pragma unroll
        for (int dx = 0; dx < 3; ++dx)
          in9[dy*3+dx] = lp[dy*20 + dx];
      #pragma unroll
      for (int o = 0; o < 4; ++o) {
        const float* wp = wc + (o*128 + ic)*9;  // SGPR-uniform -> s_load
        #pragma unroll
        for (int k = 0; k < 9; ++k)
          acc[o] = fmaf(in9[k], wp[k], acc[o]);
      }
    }
  }

  // epilogue identical order to v1 (verified bit-exact): mask before pool,
  // x-pair via shfl_xor(1) (x bit0 = lane bit0), y-pair via shfl_xor(16) (y bit0 = lane bit4)
  int y_out = yt*8 + y;
  bool writer = ((x & 1) == 0) && ((y & 1) == 0);
  #pragma unroll
  for (int o = 0; o < 4; ++o) {
    int oc = ocb + o;
    size_t base = (size_t)(b*128 + oc)*256 + y_out*16 + x;
    float m = m3[base] + acc[o] + bias[oc];
    float spk = (m >= 1.0f) ? 1.0f : 0.0f;
    m3[base] = m - spk;
    float s = spk * mf2[base];
    s += __shfl_xor(s, 1);
    s += __shfl_xor(s, 16);
    if (writer)
      p3[(size_t)b*8192 + oc*64 + (y_out>>1)*8 + (x>>1)] = s * 0.25f;
  }
}

// ---------------- fc1 v4: LDS-staged, order-preserving serial chain ----------------
// grid 256 = ug(128: 8 u) x bg(2: 16 b); block 128 = 8 u-lanes x 16 b
__global__ __launch_bounds__(128) void k_fc1v4(const float* __restrict__ p3,
    const float* __restrict__ w, const float* __restrict__ bias,
    const float* __restrict__ mask, float* __restrict__ c1, float* __restrict__ sf1) {
  const float4* w4  = (const float4*)w;
  const float4* p34 = (const float4*)p3;
  int ug = blockIdx.x >> 1;
  int bg = blockIdx.x & 1;
  int u0 = ug * 8, b0 = bg * 16;
  int t = threadIdx.x;
  int u_l = t & 7, b_sub = t >> 3;       // u fastest -> coalesced c1/sf1 epilogue

  __shared__ float4 lds4[8*130 + 16*129];  // w | s = 49.7 KB
  float4* wl = lds4;
  float4* sl = lds4 + 8*130;

  float acc = 0.f;
  for (int kc = 0; kc < 16; ++kc) {
    __syncthreads();
    #pragma unroll
    for (int j0 = 0; j0 < 1024; j0 += 128) {
      int j = j0 + t;
      int u_i = j >> 7, k4 = j & 127;
      wl[u_i*130 + k4] = w4[(size_t)(u0 + u_i)*2048 + kc*128 + k4];
    }
    #pragma unroll
    for (int j0 = 0; j0 < 2048; j0 += 128) {
      int j = j0 + t;
      int b_i = j >> 7, k4 = j & 127;
      sl[b_i*129 + k4] = p34[(size_t)(b0 + b_i)*2048 + kc*128 + k4];
    }
    __syncthreads();
    const float4* wp = wl + u_l*130;
    const float4* sp = sl + b_sub*129;
    #pragma unroll 8
    for (int k4 = 0; k4 < 128; ++k4) {
      float4 wv = wp[k4];
      float4 sv = sp[k4];
      acc = fmaf(wv.x, sv.x, acc);
      acc = fmaf(wv.y, sv.y, acc);
      acc = fmaf(wv.z, sv.z, acc);
      acc = fmaf(wv.w, sv.w, acc);
    }
  }

  int u = u0 + u_l, b = b0 + b_sub;
  int mi = b * 1024 + u;
  float m = c1[mi] + acc + bias[u];
  float spk = (m >= 1.0f) ? 1.0f : 0.0f;
  c1[mi] = m - spk;
  sf1[mi] = spk * mask[mi];
}

// ---------------- fc2 (32x1024 @ 1024x10^T) + LIF(c2) -> out ----------------
__global__ __launch_bounds__(256) void k_fc2(const float* __restrict__ sf1,
    const float* __restrict__ w, const float* __restrict__ bias,
    float* __restrict__ c2, float* __restrict__ out) {
  int idx = blockIdx.x * 256 + threadIdx.x;
  if (idx >= 320) return;
  int u = idx >> 5;      // 0..9
  int b = idx & 31;
  const float4* wp = (const float4*)(w + u * 1024);
  const float4* sp = (const float4*)(sf1 + b * 1024);
  float acc = 0.f;
  #pragma unroll 4
  for (int i = 0; i < 256; ++i) {
    float4 a = wp[i];
    float4 s = sp[i];
    acc = fmaf(a.x, s.x, acc);
    acc = fmaf(a.y, s.y, acc);
    acc = fmaf(a.z, s.z, acc);
    acc = fmaf(a.w, s.w, acc);
  }
  int mi = b * 10 + u;
  float m = c2[mi] + acc + bias[u];
  float spk = (m >= 1.0f) ? 1.0f : 0.0f;
  m -= spk;
  c2[mi] = m;
  out[mi] = m;   // final timestep's write is the answer
}

extern "C" void kernel_launch(void* const* d_in, const int* in_sizes, int n_in,
                              void* d_out, int out_size, void* d_ws, size_t ws_size,
                              hipStream_t stream) {
  const float* X   = (const float*)d_in[0];
  const float* w1  = (const float*)d_in[1];
  const float* b1  = (const float*)d_in[2];
  const float* w2  = (const float*)d_in[3];
  const float* b2  = (const float*)d_in[4];
  const float* w3  = (const float*)d_in[5];
  const float* b3  = (const float*)d_in[6];
  const float* fw1 = (const float*)d_in[7];
  const float* fb1 = (const float*)d_in[8];
  const float* fw2 = (const float*)d_in[9];
  const float* fb2 = (const float*)d_in[10];
  const float* mf1 = (const float*)d_in[11];
  const float* mf2 = (const float*)d_in[12];
  const float* mc1 = (const float*)d_in[13];
  float* out = (float*)d_out;

  float* ws    = (float*)d_ws;
  float* A1    = ws + OFF_A1;
  float* m1    = ws + OFF_M1;
  float* s1pad = ws + OFF_S1P;
  float* m2    = ws + OFF_M2;
  float* p2pad = ws + OFF_P2P;
  float* m3    = ws + OFF_M3;
  float* p3    = ws + OFF_P3;
  float* c1    = ws + OFF_C1;
  float* sf1   = ws + OFF_SF1;
  float* c2    = ws + OFF_C2;

  // ws is poisoned 0xAA before every timed call: zero EVERYTHING after A1
  // (LIF state + padded-buffer borders). N_ZERO = OFF_C2+N_C2-OFF_M1 — the
  // round-11/12 version was short by N_L1 and left m3/c1/c2 poisoned (absmax 3e-13).
  hipMemsetAsync(m1, 0, (size_t)N_ZERO * 4, stream);

  // conv1 output is timestep-invariant: compute once.
  k_conv1<<<N_L1/256, 256, 0, stream>>>(X, w1, b1, A1);

  for (int t = 0; t < T_STEPS; ++t) {
    k_lif1<<<N_L1/4/256, 256, 0, stream>>>((const float4*)A1, (const float4*)mf1,
                                           (float4*)m1, s1pad);
    k_conv2<<<1024, 256, 0, stream>>>(s1pad, w2, b2, m2, p2pad);
    k_conv3<<<1024, 256, 0, stream>>>(p2pad, w3, b3, mf2, m3, p3);
    k_fc1v4<<<256, 128, 0, stream>>>(p3, fw1, fb1, mc1, c1, sf1);
    k_fc2<<<2, 256, 0, stream>>>(sf1, fw2, fb2, c2, out);
  }
}